// Round 12
// baseline (414.984 us; speedup 1.0000x reference)
//
#include <hip/hip_runtime.h>
#include <cstdio>
#include <cstdint>

// RGCN block, FUSED aggregation+GEMM (v2):
//   per 64-dst block, for r in 0..8 (8 rels + root):
//     wave-parallel gather of mean_r(x[src]) into swizzled 32 KB LDS tile
//     (relation-major CSR -> each wave's 8 groups are ONE contiguous ebuf run;
//      src ids preloaded into lanes, x-rows loaded in batches of 4 for ILP),
//     then MFMA tile @ W_r (direct from L2-hot wbfT), acc in VGPRs.
//   Epilogue: out = acc + bias, BN stats via shfl+atomics. k_final: BN+PReLU+res.
// Round-4 fusion failed on TLP (1.5 blk/CU) + serial loads; v2: 782x8 waves,
// batched independent loads. Kills k_agg(142us) + k_gemm(120us) + 445 MB M traffic.
// NOTE: harness delivers integer inputs as int32 (edge_index int64 -> const int*).

constexpr int kN  = 50000;   // nodes
constexpr int kE  = 800000;  // edges
constexpr int kR  = 8;       // relations
constexpr int kC  = 256;     // channels
constexpr int kK  = 2304;    // wbfT k-extent (8 rels + root)
constexpr int kNB = 782;     // ceil(kN/64) dst blocks

typedef __attribute__((ext_vector_type(8))) short bf16x8;
typedef __attribute__((ext_vector_type(4))) float f32x4;
typedef __attribute__((ext_vector_type(2))) unsigned int u32x2;

__device__ __forceinline__ unsigned short f2bf(float f) {
  unsigned u = __builtin_bit_cast(unsigned, f);
  u = u + 0x7FFFu + ((u >> 16) & 1u);
  return (unsigned short)(u >> 16);
}
__device__ __forceinline__ float bf2f(unsigned short s) {
  unsigned u = ((unsigned)s) << 16;
  return __builtin_bit_cast(float, u);
}

// ---- per-edge counts: cnt[rel*N+dst] ----
__global__ void k_count(const int* __restrict__ ei, const float* __restrict__ ea,
                        int* __restrict__ cnt) {
  int e = blockIdx.x * blockDim.x + threadIdx.x;
  if (e >= kE) return;
  int dst = ei[kE + e];
  int rel = (int)ea[(size_t)e * 5 + 4];
  if ((unsigned)dst >= (unsigned)kN || (unsigned)rel >= (unsigned)kR) return;
  atomicAdd(&cnt[rel * kN + dst], 1);
}

// ---- convert x -> contiguous bf16 [kN][kC] ----
__global__ void k_convert_x(const float* __restrict__ x, unsigned short* __restrict__ xbf) {
  int i = (blockIdx.x * blockDim.x + threadIdx.x) * 4;
  if (i >= kN * kC) return;
  float4 v = *(const float4*)(x + i);
  ushort4 o;
  o.x = f2bf(v.x); o.y = f2bf(v.y); o.z = f2bf(v.z); o.w = f2bf(v.w);
  *(ushort4*)(xbf + i) = o;
}

// ---- convert W+root -> bf16 transposed: wbfT[c][k], k<2048: W[k>>8][k&255][c]; else root[k-2048][c] ----
__global__ void k_convert_w(const float* __restrict__ W, const float* __restrict__ root,
                            unsigned short* __restrict__ wbfT) {
  int t = blockIdx.x * blockDim.x + threadIdx.x;   // c*kK + k
  if (t >= kC * kK) return;
  int c = t / kK, k = t - c * kK;
  float v;
  if (k < kR * kC) {
    int r = k >> 8, kk = k & 255;
    v = W[(size_t)r * kC * kC + (size_t)kk * kC + c];
  } else {
    v = root[(size_t)(k - kR * kC) * kC + c];
  }
  wbfT[(size_t)c * kK + k] = f2bf(v);
}

// ---- group bases, RELATION-MAJOR contiguous per (r, 64-dst chunk) ----
// One wave per chunk (8*782 = 6256 chunks), one group per lane; wave-scan +
// one atomicAdd -> the 64 groups of a chunk are contiguous in ebuf, which is
// exactly what each fused-kernel wave consumes as one run.
__global__ void k_grp(const int* __restrict__ cnt, int* __restrict__ cursor,
                      int* __restrict__ gst, int* __restrict__ cur) {
  int wid = (blockIdx.x * blockDim.x + threadIdx.x) >> 6;
  int lane = threadIdx.x & 63;
  if (wid >= kR * kNB) return;
  int r = wid / kNB, db = (wid - r * kNB) * 64;
  int d = db + lane;
  int c = (d < kN) ? cnt[r * kN + d] : 0;
  int incl = c;
#pragma unroll
  for (int s = 1; s < 64; s <<= 1) {
    int v = __shfl_up(incl, s);
    if (lane >= s) incl += v;
  }
  int wtot = __shfl(incl, 63);
  int base = 0;
  if (lane == 63) base = atomicAdd(cursor, wtot);
  base = __shfl(base, 63);
  if (d < kN) { int o = base + incl - c; gst[r * kN + d] = o; cur[r * kN + d] = o; }
}

// ---- fill CSR edge records (u16 src) ----
__global__ void k_fill(const int* __restrict__ ei, const float* __restrict__ ea,
                       int* __restrict__ cur, unsigned short* __restrict__ ebuf) {
  int e = blockIdx.x * blockDim.x + threadIdx.x;
  if (e >= kE) return;
  int src = ei[e];
  int dst = ei[kE + e];
  int rel = (int)ea[(size_t)e * 5 + 4];
  if ((unsigned)dst >= (unsigned)kN || (unsigned)rel >= (unsigned)kR) return;
  int pos = atomicAdd(&cur[rel * kN + dst], 1);
  ebuf[pos] = (unsigned short)src;
}

// ---- FUSED gather + GEMM + stats ----
// 782 blocks x 512 thr (8 waves). Tile: 64 dsts x 256 out cols.
// LDS Ms[64][256] bf16 (32 KB), XOR-swizzled (byte ^= (row&7)<<4).
__global__ __launch_bounds__(512) void k_fused(const unsigned short* __restrict__ xbf,
                                               const unsigned short* __restrict__ wbfT,
                                               const unsigned short* __restrict__ ebuf,
                                               const int* __restrict__ gst,
                                               const int* __restrict__ cnt,
                                               const float* __restrict__ bias,
                                               float* __restrict__ out,
                                               float* __restrict__ cs,
                                               float* __restrict__ csq) {
  __shared__ __align__(16) unsigned short Ms[64 * 256];
  const int tid = threadIdx.x, lane = tid & 63, wv = tid >> 6;
  const int d0 = blockIdx.x * 64;
  const int dbase = d0 + wv * 8;          // this wave gathers 8 dsts
  f32x4 acc[4][2] = {};                    // 64 rows x 32 cols per wave (cols wv*32..)

  auto ms_store = [&](int row, float s0, float s1, float s2, float s3) {
    unsigned lo = (unsigned)f2bf(s0) | ((unsigned)f2bf(s1) << 16);
    unsigned hi = (unsigned)f2bf(s2) | ((unsigned)f2bf(s3) << 16);
    unsigned byte = (unsigned)(row * 512) + (((unsigned)(lane * 8)) ^ ((unsigned)((row & 7) << 4)));
    *(u32x2*)((char*)Ms + byte) = u32x2{lo, hi};
  };

  for (int r = 0; r < 9; ++r) {
    // ---------- gather phase ----------
    if (r < kR) {
      int vc = kN - dbase; vc = vc < 0 ? 0 : (vc > 8 ? 8 : vc);
      int gidx = 0;
      if (vc > 0) {
        int gb = r * kN + dbase;
        int myst = 0, myen = 0;
        if (lane < vc) { myst = gst[gb + lane]; myen = myst + cnt[gb + lane]; }
        int runSt = __shfl(myst, 0);
        int runEn = __shfl(myen, vc - 1);
        int curSt = runSt;
        int curEn = __shfl(myen, 0);
        float s0 = 0.f, s1 = 0.f, s2 = 0.f, s3 = 0.f;
        for (int base = runSt; base < runEn; base += 64) {
          int p = base + lane;
          int srcl = (p < runEn) ? (int)ebuf[p] : 0;   // preload run's src ids
          int nn = runEn - base; if (nn > 64) nn = 64;
          for (int q = 0; q < nn; q += 4) {
            int i0 = __shfl(srcl, q);
            int i1 = __shfl(srcl, (q + 1) & 63);
            int i2 = __shfl(srcl, (q + 2) & 63);
            int i3 = __shfl(srcl, (q + 3) & 63);
            // 4 independent 512-B row loads issued back-to-back (ILP)
            ushort4 v0 = *(const ushort4*)(xbf + (size_t)i0 * kC + lane * 4);
            ushort4 v1 = *(const ushort4*)(xbf + (size_t)i1 * kC + lane * 4);
            ushort4 v2 = *(const ushort4*)(xbf + (size_t)i2 * kC + lane * 4);
            ushort4 v3 = *(const ushort4*)(xbf + (size_t)i3 * kC + lane * 4);
            ushort4 vv[4] = {v0, v1, v2, v3};
#pragma unroll
            for (int i = 0; i < 4; ++i) {
              if (q + i >= nn) break;
              int pe = base + q + i;
              while (pe >= curEn) {                      // finalize group(s), wave-uniform
                int c = curEn - curSt;
                float sc = c > 0 ? 1.f / (float)c : 0.f;
                ms_store(wv * 8 + gidx, s0 * sc, s1 * sc, s2 * sc, s3 * sc);
                s0 = s1 = s2 = s3 = 0.f;
                ++gidx;
                curSt = curEn;
                curEn = __shfl(myen, gidx < vc ? gidx : vc - 1);
              }
              s0 += bf2f(vv[i].x); s1 += bf2f(vv[i].y);
              s2 += bf2f(vv[i].z); s3 += bf2f(vv[i].w);
            }
          }
        }
        // finalize trailing groups (incl. empties)
        while (gidx < vc) {
          int c = curEn - curSt;
          float sc = c > 0 ? 1.f / (float)c : 0.f;
          ms_store(wv * 8 + gidx, s0 * sc, s1 * sc, s2 * sc, s3 * sc);
          s0 = s1 = s2 = s3 = 0.f;
          ++gidx;
          if (gidx < vc) { curSt = curEn; curEn = __shfl(myen, gidx); }
        }
      }
      for (int g = gidx < 0 ? 0 : (vc > 0 ? vc : 0); g < 8; ++g)
        ms_store(wv * 8 + g, 0.f, 0.f, 0.f, 0.f);       // pad dsts -> zero rows
    } else {
      // root "relation": identity rows, raw bf16 copy
      for (int g = 0; g < 8; ++g) {
        int d = dbase + g;
        unsigned lo = 0, hi = 0;
        if (d < kN) {
          ushort4 v = *(const ushort4*)(xbf + (size_t)d * kC + lane * 4);
          lo = (unsigned)v.x | ((unsigned)v.y << 16);
          hi = (unsigned)v.z | ((unsigned)v.w << 16);
        }
        int row = wv * 8 + g;
        unsigned byte = (unsigned)(row * 512) + (((unsigned)(lane * 8)) ^ ((unsigned)((row & 7) << 4)));
        *(u32x2*)((char*)Ms + byte) = u32x2{lo, hi};
      }
    }
    __syncthreads();

    // ---------- MFMA phase: acc += Ms @ W_r ----------
    const int rbase = r * 256;
#pragma unroll
    for (int kk = 0; kk < 256; kk += 32) {
      const int koff = kk + (lane >> 4) * 8;
      bf16x8 a[4], b[2];
#pragma unroll
      for (int i = 0; i < 4; ++i) {
        int row = i * 16 + (lane & 15);
        unsigned byte = (unsigned)(row * 512) + (((unsigned)(koff * 2)) ^ ((unsigned)((row & 7) << 4)));
        a[i] = *(const bf16x8*)((const char*)Ms + byte);
      }
#pragma unroll
      for (int j = 0; j < 2; ++j) {
        int col = wv * 32 + j * 16 + (lane & 15);
        b[j] = *(const bf16x8*)(wbfT + (size_t)col * kK + rbase + koff);   // L2-hot
      }
#pragma unroll
      for (int i = 0; i < 4; ++i)
#pragma unroll
        for (int j = 0; j < 2; ++j)
          acc[i][j] = __builtin_amdgcn_mfma_f32_16x16x32_bf16(a[i], b[j], acc[i][j], 0, 0, 0);
    }
    __syncthreads();
  }

  // ---------- epilogue: out = acc + bias; column stats (pad rows have acc==0) ----------
#pragma unroll
  for (int j = 0; j < 2; ++j) {
    int col = wv * 32 + j * 16 + (lane & 15);
    float bv = bias[col];
    float s = 0.f, ss = 0.f;
#pragma unroll
    for (int i = 0; i < 4; ++i) {
      int rb = d0 + i * 16 + (lane >> 4) * 4;
#pragma unroll
      for (int q = 0; q < 4; ++q) {
        float v = acc[i][j][q];
        s += v; ss += v * v;
        int row = rb + q;
        if (row < kN) out[(size_t)row * kC + col] = v + bv;
      }
    }
    s  += __shfl_xor(s, 16);  s  += __shfl_xor(s, 32);
    ss += __shfl_xor(ss, 16); ss += __shfl_xor(ss, 32);
    if (lane < 16) { atomicAdd(&cs[col], s); atomicAdd(&csq[col], ss); }
  }
}

// ---- BN normalize + PReLU + residual (stats are bias-free; shift mu by bias) ----
__global__ void k_final(float* __restrict__ h, const float* __restrict__ x,
                        const float* __restrict__ cs, const float* __restrict__ csq,
                        const float* __restrict__ bias,
                        const float* __restrict__ gamma, const float* __restrict__ beta,
                        const float* __restrict__ prelu) {
  int idx = (blockIdx.x * blockDim.x + threadIdx.x) * 4;
  if (idx >= kN * kC) return;
  int col = idx & 255;
  const float inv_n = 1.0f / (float)kN;
  float a = prelu[0];
  float4 hv = *(float4*)(h + idx);
  float4 xv = *(const float4*)(x + idx);
  float hr[4] = {hv.x, hv.y, hv.z, hv.w};
  float xr[4] = {xv.x, xv.y, xv.z, xv.w};
#pragma unroll
  for (int j = 0; j < 4; ++j) {
    int c = col + j;
    float mu_raw = cs[c] * inv_n;
    float var = csq[c] * inv_n - mu_raw * mu_raw;
    float mu  = mu_raw + bias[c];          // h was stored with bias added
    float k   = gamma[c] * rsqrtf(var + 1e-5f);
    float v   = (hr[j] - mu) * k + beta[c];
    v = v > 0.f ? v : a * v;
    hr[j] = v + xr[j];
  }
  *(float4*)(h + idx) = make_float4(hr[0], hr[1], hr[2], hr[3]);
}

extern "C" void kernel_launch(void* const* d_in, const int* in_sizes, int n_in,
                              void* d_out, int out_size, void* d_ws, size_t ws_size,
                              hipStream_t stream) {
  const float* x     = (const float*)d_in[0];
  const int*   ei    = (const int*)d_in[1];     // int64 in ref -> int32 from harness
  const float* ea    = (const float*)d_in[2];
  const float* W     = (const float*)d_in[3];
  const float* root  = (const float*)d_in[4];
  const float* bias  = (const float*)d_in[5];
  const float* gamma = (const float*)d_in[6];
  const float* beta  = (const float*)d_in[7];
  const float* prelu = (const float*)d_in[8];
  float* out = (float*)d_out;
  char* ws = (char*)d_ws;

  size_t o = 0;
  auto alloc = [&](size_t sz) { size_t r = o; o += (sz + 255) & ~(size_t)255; return r; };
  size_t xbf_o  = alloc((size_t)kN * kC * 2);        // 25.6 MB
  size_t wbf_o  = alloc((size_t)kC * kK * 2);        // 1.2 MB
  size_t cnt_o  = alloc((size_t)kR * kN * 4);        // 1.6 MB
  size_t cs_o   = alloc(256 * 4);
  size_t csq_o  = alloc(256 * 4);
  size_t csr_o  = alloc(256);                        // global cursor (1 int)
  size_t zend   = o;                                 // end of must-zero region
  size_t gst_o  = alloc((size_t)kR * kN * 4);        // persistent group starts
  size_t cur_o  = alloc((size_t)kR * kN * 4);        // mutable cursors
  size_t eb_o   = alloc((size_t)kE * 2);             // u16 src records
  if (o > ws_size) {
    fprintf(stderr, "[RGCN kernel] ws too small: need %zu have %zu\n", o, ws_size);
    return;
  }

  unsigned short* xbf  = (unsigned short*)(ws + xbf_o);
  unsigned short* wbfT = (unsigned short*)(ws + wbf_o);
  int*   cnt    = (int*)(ws + cnt_o);
  float* cs     = (float*)(ws + cs_o);
  float* csq    = (float*)(ws + csq_o);
  int*   cursor = (int*)(ws + csr_o);
  int*   gst    = (int*)(ws + gst_o);
  int*   cur    = (int*)(ws + cur_o);
  unsigned short* ebuf = (unsigned short*)(ws + eb_o);

  hipMemsetAsync(ws + cnt_o, 0, zend - cnt_o, stream);           // cnt/cs/csq/cursor
  k_count<<<(kE + 255) / 256, 256, 0, stream>>>(ei, ea, cnt);
  k_convert_x<<<(kN * kC / 4) / 256, 256, 0, stream>>>(x, xbf);
  k_convert_w<<<(kC * kK + 255) / 256, 256, 0, stream>>>(W, root, wbfT);
  k_grp<<<(kR * kNB * 64 + 255) / 256, 256, 0, stream>>>(cnt, cursor, gst, cur);
  k_fill<<<(kE + 255) / 256, 256, 0, stream>>>(ei, ea, cur, ebuf);
  k_fused<<<kNB, 512, 0, stream>>>(xbf, wbfT, ebuf, gst, cnt, bias, out, cs, csq);
  k_final<<<(kN * kC / 4) / 256, 256, 0, stream>>>(out, x, cs, csq, bias, gamma, beta, prelu);
}